// Round 7
// baseline (868.613 us; speedup 1.0000x reference)
//
#include <hip/hip_runtime.h>

// Problem dims (fixed by setup_inputs): x[4,2048,4096] f32, W[4096,4096] f32,
// lora_A[16,4096], lora_B[4096,16], sigma[16]. out[4,2048,4096] f32.
// out = x @ (W + SCALING * (B*diag(sigma_masked)) @ A)^T
#define D_DIM 4096
#define R_DIM 16
#define SCALING_F 1.0f          // 16.0/16
#define THRESH 0.01f

typedef __attribute__((ext_vector_type(8))) short short8;   // 8 bf16 = 4 VGPRs
typedef __attribute__((ext_vector_type(4))) float floatx4;  // MFMA C/D

__device__ __forceinline__ unsigned int f2bf(float f) {
  union { float f; unsigned int u; } v; v.f = f;
  unsigned int u = v.u;
  u += 0x7FFFu + ((u >> 16) & 1u);   // round-to-nearest-even
  return u >> 16;
}

// ---------- fused prep: x f32->bf16 AND W_eff build, one launch ----------
__global__ __launch_bounds__(256) void prep_kernel(
    const float* __restrict__ x, unsigned int* __restrict__ xb, int n8,
    int nxblocks,
    const float* __restrict__ W, const float* __restrict__ lA,
    const float* __restrict__ lB, const float* __restrict__ sigma,
    unsigned int* __restrict__ wb) {
  __shared__ float Bs[R_DIM];
  int b = blockIdx.x;
  if (b < nxblocks) {
    int idx = b * 256 + threadIdx.x;
    if (idx >= n8) return;
    const float4* xp = (const float4*)x;
    float4 v0 = xp[2 * idx];
    float4 v1 = xp[2 * idx + 1];
    uint4 o;
    o.x = f2bf(v0.x) | (f2bf(v0.y) << 16);
    o.y = f2bf(v0.z) | (f2bf(v0.w) << 16);
    o.z = f2bf(v1.x) | (f2bf(v1.y) << 16);
    o.w = f2bf(v1.z) | (f2bf(v1.w) << 16);
    ((uint4*)xb)[idx] = o;
  } else {
    int idx = (b - nxblocks) * 256 + threadIdx.x;  // float4 index
    int o  = idx >> 10;                             // row (uniform per block)
    int dq = idx & 1023;
    if (threadIdx.x < R_DIM) {
      float s = sigma[threadIdx.x];
      s = (fabsf(s) >= THRESH) ? s : 0.0f;
      Bs[threadIdx.x] = lB[o * R_DIM + threadIdx.x] * s * SCALING_F;
    }
    __syncthreads();
    float4 acc = ((const float4*)W)[idx];
#pragma unroll
    for (int r = 0; r < R_DIM; ++r) {
      float bb = Bs[r];
      float4 a = ((const float4*)(lA + (size_t)r * D_DIM))[dq];
      acc.x += bb * a.x; acc.y += bb * a.y; acc.z += bb * a.z; acc.w += bb * a.w;
    }
    uint2 p;
    p.x = f2bf(acc.x) | (f2bf(acc.y) << 16);
    p.y = f2bf(acc.z) | (f2bf(acc.w) << 16);
    ((uint2*)wb)[idx] = p;
  }
}

// =====================================================================
// GEMM: C[M,N] = A[M,K] * B[N,K]^T, bf16 in, f32 out.
// 256x256 tile, BK=64, 8 waves (2M x 4N), 512 threads, 128 KiB LDS.
//
// TWO phases per K-tile (R6 had four): each phase = {stage 4 x
// global_load_lds; vmcnt(8); s_barrier; sub-region1: 16 MFMA interleaved
// (sgb {1R,2M}) with 8 ds_reads; FENCE; sub-region2: 16 MFMA interleaved
// (sgb {1R,4M}) with 4 ds_reads}. Halves barrier/vmcnt clusters vs R6
// (the measured residual: phase=1003cyc vs 621 MFMA floor at 60% MfmaUtil).
//
// LDS map (bytes): A-buf0 @0, A-buf1 @32768, B-buf0 @65536, B-buf1 @98304;
// within a buf: first-half slot (A0/B0) @+0, second (A1/B1) @+16384.
// Row permutation: A LDS row = qm*128 + wm*64 + i ; B: qn*128 + wn*32 + i.
// 16B-granule XOR swizzle: slot s holds kgroup s^(row&7); inverse applied
// to GLOBAL source addr (linear LDS dest), same XOR on ds_read. 0 conflicts.
//
// Schedule per K-tile t (alpha then beta phase), frame = 2 tiles (e=2f par0,
// o=2f+1 par1) for static buffer names:
//  alpha(t): stage A1(t+1), B0(t+2) | reads: afY<-A1(t), bf0nxt<-B0(t+1)
//            MFMA c1=(0,0) afX*bf0cur ; c2=(0,1) afX*bf1
//  beta(t):  stage A0(t+2), B1(t+2) | reads: afX<-A0(t+1), bf1<-B1(t+1)
//            MFMA c3=(1,1) afY*bf1 ; c4=(1,0) afY*bf0cur
// bf0 register-double-buffered (bf0A=even tiles, bf0B=odd); afX/afY/bf1
// single (overwrite ordered after consuming MFMA group by sub-fences).
// Ledger (verified): stages at phase p overlap only reads of p-1; every
// same-LDS-slot previous read is at p-2 (barrier between). Reads at p use
// data staged at p-2, drained by p's vmcnt(8) (4 own + 4 prev in flight).
// Tail stages wrap &8191 (read-but-unused). Prologue reproduces the
// steady-state vmcnt invariant exactly.
// =====================================================================

__device__ __forceinline__ void stage16(const void* g, void* l) {
  __builtin_amdgcn_global_load_lds(
      (const __attribute__((address_space(1))) void*)g,
      (__attribute__((address_space(3))) void*)l, 16, 0, 0);
}

#define FENCE() __builtin_amdgcn_sched_barrier(0)

#define WAIT_VM8_BAR()                                  \
  FENCE();                                              \
  asm volatile("s_waitcnt vmcnt(8)" ::: "memory");      \
  __builtin_amdgcn_s_barrier();                         \
  FENCE()

// Interleave patterns for a fenced {ds_read + MFMA} sub-region.
__device__ __forceinline__ void sgb_8reads() {   // 8 DS_READ + 16 MFMA
#pragma unroll
  for (int i = 0; i < 8; ++i) {
    __builtin_amdgcn_sched_group_barrier(0x100, 1, 0);
    __builtin_amdgcn_sched_group_barrier(0x008, 2, 0);
  }
}
__device__ __forceinline__ void sgb_4reads() {   // 4 DS_READ + 16 MFMA
#pragma unroll
  for (int i = 0; i < 4; ++i) {
    __builtin_amdgcn_sched_group_barrier(0x100, 1, 0);
    __builtin_amdgcn_sched_group_barrier(0x008, 4, 0);
  }
}

#define LOADA_TO(DST, BUF, QM)                                                 \
  _Pragma("unroll") for (int t = 0; t < 4; ++t) {                              \
    DST[t][0] = *(const short8*)(aRd0 + (BUF)*32768 + (QM)*16384 + t*2048);    \
    DST[t][1] = *(const short8*)(aRd1 + (BUF)*32768 + (QM)*16384 + t*2048);    \
  }

#define LOADB_TO(DST, BUF, QN)                                                 \
  _Pragma("unroll") for (int j = 0; j < 2; ++j) {                              \
    DST[j][0] = *(const short8*)(bRd0 + (BUF)*32768 + (QN)*16384 + j*2048);    \
    DST[j][1] = *(const short8*)(bRd1 + (BUF)*32768 + (QN)*16384 + j*2048);    \
  }

#define MFMA16(QM, QN, AF, BF)                                                 \
  _Pragma("unroll") for (int t = 0; t < 4; ++t)                                \
  _Pragma("unroll") for (int j = 0; j < 2; ++j)                                \
    acc[QM][QN][t][j] = __builtin_amdgcn_mfma_f32_16x16x32_bf16(               \
        AF[t][0], BF[j][0], acc[QM][QN][t][j], 0, 0, 0);                       \
  _Pragma("unroll") for (int t = 0; t < 4; ++t)                                \
  _Pragma("unroll") for (int j = 0; j < 2; ++j)                                \
    acc[QM][QN][t][j] = __builtin_amdgcn_mfma_f32_16x16x32_bf16(               \
        AF[t][1], BF[j][1], acc[QM][QN][t][j], 0, 0, 0);

__global__ __launch_bounds__(512, 2) void gemm_bt_kernel(
    const unsigned short* __restrict__ A,   // x bf16 [M, K]
    const unsigned short* __restrict__ B,   // W_eff bf16 [N, K]
    float* __restrict__ C, int M) {
  __shared__ __align__(16) char lds[131072];

  const int tid  = threadIdx.x;
  const int lane = tid & 63;
  const int wave = tid >> 6;      // 0..7
  const int wm   = wave >> 2;     // 0..1 (128 rows each)
  const int wn   = wave & 3;      // 0..3 (64 cols each)
  const int lrow = lane & 15;
  const int lq   = lane >> 4;     // 0..3
  const int r7   = lrow & 7;

  // XCD-bijective block swizzle (gridDim.x % 8 == 0 here: 512 blocks).
  const int bid = blockIdx.x;
  const int cpx = gridDim.x >> 3;
  const int swz = (bid & 7) * cpx + (bid >> 3);
  const int m0 = (swz >> 4) << 8;           // 16 n-tiles (D_DIM/256)
  const int n0 = (swz & 15) << 8;

  // ---- staging source bases (per thread) ----
  const int rr8  = tid >> 3;                               // 0..63
  const int kgsw = (tid & 7) ^ (rr8 & 7);
  const char* aSrc = (const char*)A + ((size_t)(m0 + rr8) << 13) + (kgsw << 4);
  const int nrow = (rr8 & 31) | ((rr8 & 32) << 1);
  const char* bSrc = (const char*)B + ((size_t)(n0 + nrow) << 13) + (kgsw << 4);
  char* ldsW = lds + wave * 1024;           // wave-uniform dest base

  // ---- fragment read bases (per lane) ----
  const char* aRd0 = lds + wm * 8192 + lrow * 128 + ((lq ^ r7) << 4);
  const char* aRd1 = lds + wm * 8192 + lrow * 128 + (((4 | lq) ^ r7) << 4);
  const char* bRd0 = lds + 65536 + wn * 4096 + lrow * 128 + ((lq ^ r7) << 4);
  const char* bRd1 = lds + 65536 + wn * 4096 + lrow * 128 + (((4 | lq) ^ r7) << 4);

  short8 afX[4][2], afY[4][2];          // A0 / A1 fragments (current tile)
  short8 bf0A[2][2], bf0B[2][2];        // B0 fragments (tile parity)
  short8 bf1[2][2];                     // B1 fragments (current tile)
  floatx4 acc[2][2][4][2] = {};         // [qm][qn][t][j]

  // ---- prologue (reproduces steady vmcnt(8) invariant) ----
  stage16(aSrc,                      ldsW + 0);        // A0(0)
  stage16(aSrc + (128 << 13),        ldsW + 8192);
  stage16(bSrc,                      ldsW + 65536);    // B0(0)
  stage16(bSrc + (128 << 13),        ldsW + 73728);
  stage16(bSrc + (32 << 13),         ldsW + 81920);    // B1(0)
  stage16(bSrc + (160 << 13),        ldsW + 90112);
  stage16(aSrc + (64 << 13),         ldsW + 16384);    // A1(0)   ["alpha(-1)"]
  stage16(aSrc + (192 << 13),        ldsW + 24576);
  stage16(bSrc + 128,                ldsW + 98304);    // B0(1)
  stage16(bSrc + (128 << 13) + 128,  ldsW + 106496);
  FENCE();
  asm volatile("s_waitcnt vmcnt(4)" ::: "memory");     // first 6 landed
  __builtin_amdgcn_s_barrier();
  FENCE();
  LOADA_TO(afX, 0, 0)                                  // A0(0)
  LOADB_TO(bf0A, 0, 0)                                 // B0(0)
  LOADB_TO(bf1, 0, 1)                                  // B1(0)
  FENCE();
  stage16(aSrc + 128,                ldsW + 32768);    // A0(1)   ["beta(-1)"]
  stage16(aSrc + (128 << 13) + 128,  ldsW + 40960);
  stage16(bSrc + (32 << 13) + 128,   ldsW + 114688);   // B1(1)
  stage16(bSrc + (160 << 13) + 128,  ldsW + 122880);
  FENCE();

  int kb = 0;
#pragma unroll 1
  for (int f = 0; f < 32; ++f) {             // frame = tiles e=2f, o=2f+1
    const int k1 = kb + 128;                 // tile o (never wraps: max 8064)
    const int k2 = (kb + 256) & 8191;        // tile e+2 (wraps at tail)
    const int k3 = (kb + 384) & 8191;        // tile o+2 (wraps at tail)

    // P0 = alpha(e): stage A1(o), B0(e+2)
    stage16(aSrc + (64 << 13) + k1,  ldsW + 49152);
    stage16(aSrc + (192 << 13) + k1, ldsW + 57344);
    stage16(bSrc + k2,               ldsW + 65536);
    stage16(bSrc + (128 << 13) + k2, ldsW + 73728);
    WAIT_VM8_BAR();
    __builtin_amdgcn_s_setprio(1);
    LOADA_TO(afY, 0, 1)                 // A1(e)
    MFMA16(0, 0, afX, bf0A);            // c1 tile e
    sgb_8reads();
    FENCE();
    LOADB_TO(bf0B, 1, 0)                // B0(o)
    MFMA16(0, 1, afX, bf1);             // c2 tile e
    sgb_4reads();
    __builtin_amdgcn_s_setprio(0);
    FENCE();

    // P1 = beta(e): stage A0(e+2), B1(e+2)
    stage16(aSrc + k2,               ldsW + 0);
    stage16(aSrc + (128 << 13) + k2, ldsW + 8192);
    stage16(bSrc + (32 << 13) + k2,  ldsW + 81920);
    stage16(bSrc + (160 << 13) + k2, ldsW + 90112);
    WAIT_VM8_BAR();
    __builtin_amdgcn_s_setprio(1);
    LOADA_TO(afX, 1, 0)                 // A0(o)
    MFMA16(1, 1, afY, bf1);             // c3 tile e (uses bf1(e))
    sgb_8reads();
    FENCE();
    LOADB_TO(bf1, 1, 1)                 // B1(o)  (after c3: WAR safe)
    MFMA16(1, 0, afY, bf0A);            // c4 tile e
    sgb_4reads();
    __builtin_amdgcn_s_setprio(0);
    FENCE();

    // P2 = alpha(o): stage A1(e+2), B0(o+2)
    stage16(aSrc + (64 << 13) + k2,  ldsW + 16384);
    stage16(aSrc + (192 << 13) + k2, ldsW + 24576);
    stage16(bSrc + k3,               ldsW + 98304);
    stage16(bSrc + (128 << 13) + k3, ldsW + 106496);
    WAIT_VM8_BAR();
    __builtin_amdgcn_s_setprio(1);
    LOADA_TO(afY, 1, 1)                 // A1(o)
    MFMA16(0, 0, afX, bf0B);            // c1 tile o
    sgb_8reads();
    FENCE();
    LOADB_TO(bf0A, 0, 0)                // B0(e+2) (after prev c4: WAR safe)
    MFMA16(0, 1, afX, bf1);             // c2 tile o
    sgb_4reads();
    __builtin_amdgcn_s_setprio(0);
    FENCE();

    // P3 = beta(o): stage A0(o+2), B1(o+2)
    stage16(aSrc + k3,               ldsW + 32768);
    stage16(aSrc + (128 << 13) + k3, ldsW + 40960);
    stage16(bSrc + (32 << 13) + k3,  ldsW + 114688);
    stage16(bSrc + (160 << 13) + k3, ldsW + 122880);
    WAIT_VM8_BAR();
    __builtin_amdgcn_s_setprio(1);
    LOADA_TO(afX, 0, 0)                 // A0(e+2)
    MFMA16(1, 1, afY, bf1);             // c3 tile o
    sgb_8reads();
    FENCE();
    LOADB_TO(bf1, 0, 1)                 // B1(e+2) (after c3: WAR safe)
    MFMA16(1, 0, afY, bf0B);            // c4 tile o
    sgb_4reads();
    __builtin_amdgcn_s_setprio(0);
    FENCE();

    kb += 256;
  }

  // ---- epilogue: D row=(lq*4+rr), col=lrow within each 16x16 fragment ----
#pragma unroll
  for (int qm = 0; qm < 2; ++qm)
#pragma unroll
    for (int t = 0; t < 4; ++t)
#pragma unroll
      for (int rr = 0; rr < 4; ++rr) {
        float* cp = C +
            (size_t)(m0 + wm * 128 + qm * 64 + t * 16 + lq * 4 + rr) * D_DIM +
            n0 + wn * 64 + lrow;
#pragma unroll
        for (int qn = 0; qn < 2; ++qn)
#pragma unroll
          for (int j = 0; j < 2; ++j)
            cp[qn * 32 + j * 16] = acc[qm][qn][t][j][rr];
      }
}

extern "C" void kernel_launch(void* const* d_in, const int* in_sizes, int n_in,
                              void* d_out, int out_size, void* d_ws, size_t ws_size,
                              hipStream_t stream) {
  const float* x     = (const float*)d_in[0];  // [M, 4096], M = 8192
  const float* W     = (const float*)d_in[1];  // [4096, 4096]
  const float* lA    = (const float*)d_in[2];  // [16, 4096]
  const float* lB    = (const float*)d_in[3];  // [4096, 16]
  const float* sigma = (const float*)d_in[4];  // [16]
  float* out = (float*)d_out;

  const int M = in_sizes[0] / D_DIM;           // 8192
  // Workspace layout: x_bf16 (M*4096*2 = 64 MB) then W_eff bf16 (32 MB).
  unsigned int* xb = (unsigned int*)d_ws;
  unsigned int* wb = (unsigned int*)((char*)d_ws + (size_t)M * D_DIM * 2);

  const int n8 = in_sizes[0] / 8;              // x octets
  const int nxblocks = (n8 + 255) / 256;       // 16384
  const int nwblocks = (D_DIM * D_DIM / 4) / 256;  // 16384
  prep_kernel<<<nxblocks + nwblocks, 256, 0, stream>>>(
      x, xb, n8, nxblocks, W, lA, lB, sigma, wb);

  const int nblocks = (M / 256) * (D_DIM / 256);   // 32*16 = 512
  gemm_bt_kernel<<<nblocks, 512, 0, stream>>>(
      (const unsigned short*)xb, (const unsigned short*)wb, out, M);
}

// Round 8
// 753.473 us; speedup vs baseline: 1.1528x; 1.1528x over previous
//
#include <hip/hip_runtime.h>

// Problem dims (fixed by setup_inputs): x[4,2048,4096] f32, W[4096,4096] f32,
// lora_A[16,4096], lora_B[4096,16], sigma[16]. out[4,2048,4096] f32.
// out = x @ (W + SCALING * (B*diag(sigma_masked)) @ A)^T
#define D_DIM 4096
#define R_DIM 16
#define SCALING_F 1.0f          // 16.0/16
#define THRESH 0.01f

typedef __attribute__((ext_vector_type(8))) short short8;   // 8 bf16 = 4 VGPRs
typedef __attribute__((ext_vector_type(4))) float floatx4;  // MFMA C/D

__device__ __forceinline__ unsigned int f2bf(float f) {
  union { float f; unsigned int u; } v; v.f = f;
  unsigned int u = v.u;
  u += 0x7FFFu + ((u >> 16) & 1u);   // round-to-nearest-even
  return u >> 16;
}

// ---------- fused prep: x f32->bf16 AND W_eff build, one launch ----------
__global__ __launch_bounds__(256) void prep_kernel(
    const float* __restrict__ x, unsigned int* __restrict__ xb, int n8,
    int nxblocks,
    const float* __restrict__ W, const float* __restrict__ lA,
    const float* __restrict__ lB, const float* __restrict__ sigma,
    unsigned int* __restrict__ wb) {
  __shared__ float Bs[R_DIM];
  int b = blockIdx.x;
  if (b < nxblocks) {
    int idx = b * 256 + threadIdx.x;
    if (idx >= n8) return;
    const float4* xp = (const float4*)x;
    float4 v0 = xp[2 * idx];
    float4 v1 = xp[2 * idx + 1];
    uint4 o;
    o.x = f2bf(v0.x) | (f2bf(v0.y) << 16);
    o.y = f2bf(v0.z) | (f2bf(v0.w) << 16);
    o.z = f2bf(v1.x) | (f2bf(v1.y) << 16);
    o.w = f2bf(v1.z) | (f2bf(v1.w) << 16);
    ((uint4*)xb)[idx] = o;
  } else {
    int idx = (b - nxblocks) * 256 + threadIdx.x;  // float4 index
    int o  = idx >> 10;                             // row (uniform per block)
    int dq = idx & 1023;
    if (threadIdx.x < R_DIM) {
      float s = sigma[threadIdx.x];
      s = (fabsf(s) >= THRESH) ? s : 0.0f;
      Bs[threadIdx.x] = lB[o * R_DIM + threadIdx.x] * s * SCALING_F;
    }
    __syncthreads();
    float4 acc = ((const float4*)W)[idx];
#pragma unroll
    for (int r = 0; r < R_DIM; ++r) {
      float bb = Bs[r];
      float4 a = ((const float4*)(lA + (size_t)r * D_DIM))[dq];
      acc.x += bb * a.x; acc.y += bb * a.y; acc.z += bb * a.z; acc.w += bb * a.w;
    }
    uint2 p;
    p.x = f2bf(acc.x) | (f2bf(acc.y) << 16);
    p.y = f2bf(acc.z) | (f2bf(acc.w) << 16);
    ((uint2*)wb)[idx] = p;
  }
}

// =====================================================================
// GEMM: C[M,N] = A[M,K] * B[N,K]^T, bf16 in, f32 out.
// 256x256 tile, BK=64, 8 waves (2M x 4N), 512 threads, 128 KiB LDS.
//
// TWO phases per K-tile t (alpha, beta), ALL register prefetch distances
// = 1 phase (R7's dist-2 bf0B caused spill: WRITE_SIZE 131->367 MB).
//  alpha(t): stage A1(t+1) [2]; vmcnt(8); barrier;
//            sub1: read afY<-A1(t) [8R] || c1=(0,0) afX*bf0par {1R,2M}
//            sub2: c2=(0,1) afX*bf1  (pure 16 MFMA)
//  beta(t):  stage A0,B0,B1 (t+2) [6]; vmcnt(8); barrier;
//            sub1: read afX<-A0(t+1)[8R] + bf0other<-B0(t+1)[4R]
//                  || c3=(1,1) afY*bf1 {3R,4M}
//            sub2: read bf1<-B1(t+1)[4R] || c4=(1,0) afY*bf0par {1R,4M}
// Fragment buffers identical to the no-spill R6 set: afX, afY, bf0A/bf0B
// (parity), bf1 (single; overwrite in beta sub2 is after c3's issue).
// vmcnt FIFO (verified): alpha top drains alpha(t-1)'s 2 (= A1(t));
// beta top drains beta(t-1)'s 6 (= A0/B0/B1(t+1)) — exactly what each
// phase reads. 2 sync clusters/K-tile vs R6's 4 (the measured residual:
// phase=1003cyc vs 621cyc MFMA floor).
//
// LDS map (bytes): A-buf0 @0, A-buf1 @32768, B-buf0 @65536, B-buf1 @98304;
// slot A0/B0 @+0, A1/B1 @+16384 within each buf; buf = tile parity.
// 16B-granule XOR swizzle: slot s holds kgroup s^(row&7); inverse applied
// to GLOBAL source addr (linear LDS dest), same XOR on ds_read. 0 conflicts.
// Overwrite ledger: stages at phase p are disjoint from all reads at p-1
// (checked per slot); 2-phase-distance overwrites additionally covered by
// ~500cy HBM latency vs ~120cy ds_read in-flight window.
// Tail stages wrap &8191 (read-but-unused). Prologue reproduces the
// steady-state vmcnt invariant exactly (6 then 8 staged, vmcnt(8)).
// =====================================================================

__device__ __forceinline__ void stage16(const void* g, void* l) {
  __builtin_amdgcn_global_load_lds(
      (const __attribute__((address_space(1))) void*)g,
      (__attribute__((address_space(3))) void*)l, 16, 0, 0);
}

#define FENCE() __builtin_amdgcn_sched_barrier(0)

#define WAIT_VM8_BAR()                                  \
  FENCE();                                              \
  asm volatile("s_waitcnt vmcnt(8)" ::: "memory");      \
  __builtin_amdgcn_s_barrier();                         \
  FENCE()

// Interleave patterns for a fenced {ds_read + MFMA} sub-region.
__device__ __forceinline__ void sgb_8reads() {   // 8 DS_READ + 16 MFMA
#pragma unroll
  for (int i = 0; i < 8; ++i) {
    __builtin_amdgcn_sched_group_barrier(0x100, 1, 0);
    __builtin_amdgcn_sched_group_barrier(0x008, 2, 0);
  }
}
__device__ __forceinline__ void sgb_12reads() {  // 12 DS_READ + 16 MFMA
#pragma unroll
  for (int i = 0; i < 4; ++i) {
    __builtin_amdgcn_sched_group_barrier(0x100, 3, 0);
    __builtin_amdgcn_sched_group_barrier(0x008, 4, 0);
  }
}
__device__ __forceinline__ void sgb_4reads() {   // 4 DS_READ + 16 MFMA
#pragma unroll
  for (int i = 0; i < 4; ++i) {
    __builtin_amdgcn_sched_group_barrier(0x100, 1, 0);
    __builtin_amdgcn_sched_group_barrier(0x008, 4, 0);
  }
}

#define LOADA_TO(DST, BUF, QM)                                                 \
  _Pragma("unroll") for (int t = 0; t < 4; ++t) {                              \
    DST[t][0] = *(const short8*)(aRd0 + (BUF)*32768 + (QM)*16384 + t*2048);    \
    DST[t][1] = *(const short8*)(aRd1 + (BUF)*32768 + (QM)*16384 + t*2048);    \
  }

#define LOADB_TO(DST, BUF, QN)                                                 \
  _Pragma("unroll") for (int j = 0; j < 2; ++j) {                              \
    DST[j][0] = *(const short8*)(bRd0 + (BUF)*32768 + (QN)*16384 + j*2048);    \
    DST[j][1] = *(const short8*)(bRd1 + (BUF)*32768 + (QN)*16384 + j*2048);    \
  }

#define MFMA16(QM, QN, AF, BF)                                                 \
  _Pragma("unroll") for (int t = 0; t < 4; ++t)                                \
  _Pragma("unroll") for (int j = 0; j < 2; ++j)                                \
    acc[QM][QN][t][j] = __builtin_amdgcn_mfma_f32_16x16x32_bf16(               \
        AF[t][0], BF[j][0], acc[QM][QN][t][j], 0, 0, 0);                       \
  _Pragma("unroll") for (int t = 0; t < 4; ++t)                                \
  _Pragma("unroll") for (int j = 0; j < 2; ++j)                                \
    acc[QM][QN][t][j] = __builtin_amdgcn_mfma_f32_16x16x32_bf16(               \
        AF[t][1], BF[j][1], acc[QM][QN][t][j], 0, 0, 0);

__global__ __launch_bounds__(512, 2) void gemm_bt_kernel(
    const unsigned short* __restrict__ A,   // x bf16 [M, K]
    const unsigned short* __restrict__ B,   // W_eff bf16 [N, K]
    float* __restrict__ C, int M) {
  __shared__ __align__(16) char lds[131072];

  const int tid  = threadIdx.x;
  const int lane = tid & 63;
  const int wave = tid >> 6;      // 0..7
  const int wm   = wave >> 2;     // 0..1 (128 rows each)
  const int wn   = wave & 3;      // 0..3 (64 cols each)
  const int lrow = lane & 15;
  const int lq   = lane >> 4;     // 0..3
  const int r7   = lrow & 7;

  // XCD-bijective block swizzle (gridDim.x % 8 == 0 here: 512 blocks).
  const int bid = blockIdx.x;
  const int cpx = gridDim.x >> 3;
  const int swz = (bid & 7) * cpx + (bid >> 3);
  const int m0 = (swz >> 4) << 8;           // 16 n-tiles (D_DIM/256)
  const int n0 = (swz & 15) << 8;

  // ---- staging source bases (per thread) ----
  const int rr8  = tid >> 3;                               // 0..63
  const int kgsw = (tid & 7) ^ (rr8 & 7);
  const char* aSrc = (const char*)A + ((size_t)(m0 + rr8) << 13) + (kgsw << 4);
  const int nrow = (rr8 & 31) | ((rr8 & 32) << 1);
  const char* bSrc = (const char*)B + ((size_t)(n0 + nrow) << 13) + (kgsw << 4);
  char* ldsW = lds + wave * 1024;           // wave-uniform dest base

  // ---- fragment read bases (per lane) ----
  const char* aRd0 = lds + wm * 8192 + lrow * 128 + ((lq ^ r7) << 4);
  const char* aRd1 = lds + wm * 8192 + lrow * 128 + (((4 | lq) ^ r7) << 4);
  const char* bRd0 = lds + 65536 + wn * 4096 + lrow * 128 + ((lq ^ r7) << 4);
  const char* bRd1 = lds + 65536 + wn * 4096 + lrow * 128 + (((4 | lq) ^ r7) << 4);

  short8 afX[4][2], afY[4][2];          // A0 / A1 fragments (current tile)
  short8 bf0A[2][2], bf0B[2][2];        // B0 fragments (tile parity)
  short8 bf1[2][2];                     // B1 fragments (current tile)
  floatx4 acc[2][2][4][2] = {};         // [qm][qn][t][j]

  // ---- prologue: P1 = 6 chunks (tile0 A0,B0,B1), P2 = 8 chunks ----
  stage16(aSrc,                      ldsW + 0);        // A0(0)
  stage16(aSrc + (128 << 13),        ldsW + 8192);
  stage16(bSrc,                      ldsW + 65536);    // B0(0)
  stage16(bSrc + (128 << 13),        ldsW + 73728);
  stage16(bSrc + (32 << 13),         ldsW + 81920);    // B1(0)
  stage16(bSrc + (160 << 13),        ldsW + 90112);
  stage16(aSrc + (64 << 13),         ldsW + 16384);    // A1(0)
  stage16(aSrc + (192 << 13),        ldsW + 24576);
  stage16(aSrc + 128,                ldsW + 32768);    // A0(1) -> buf1
  stage16(aSrc + (128 << 13) + 128,  ldsW + 40960);
  stage16(bSrc + 128,                ldsW + 98304);    // B0(1) -> buf1
  stage16(bSrc + (128 << 13) + 128,  ldsW + 106496);
  stage16(bSrc + (32 << 13) + 128,   ldsW + 114688);   // B1(1) -> buf1
  stage16(bSrc + (160 << 13) + 128,  ldsW + 122880);
  FENCE();
  asm volatile("s_waitcnt vmcnt(8)" ::: "memory");     // P1 (tile0 A0,B0,B1)
  __builtin_amdgcn_s_barrier();
  FENCE();
  LOADA_TO(afX, 0, 0)                                  // A0(0)
  LOADB_TO(bf0A, 0, 0)                                 // B0(0)
  LOADB_TO(bf1, 0, 1)                                  // B1(0)
  FENCE();

  int kb = 0;
#pragma unroll 1
  for (int f = 0; f < 32; ++f) {             // frame = tiles e=2f, o=2f+1
    const int k1 = kb + 128;                 // tile o (never wraps: max 8064)
    const int k2 = (kb + 256) & 8191;        // tile e+2 (wraps at tail)
    const int k3 = (kb + 384) & 8191;        // tile o+2 (wraps at tail)

    // ---- alpha(e): stage A1(o) ----
    stage16(aSrc + (64 << 13) + k1,  ldsW + 49152);
    stage16(aSrc + (192 << 13) + k1, ldsW + 57344);
    WAIT_VM8_BAR();
    __builtin_amdgcn_s_setprio(1);
    LOADA_TO(afY, 0, 1)                 // A1(e)
    MFMA16(0, 0, afX, bf0A);            // c1 tile e
    sgb_8reads();
    FENCE();
    MFMA16(0, 1, afX, bf1);             // c2 tile e (pure MFMA)
    __builtin_amdgcn_s_setprio(0);
    FENCE();

    // ---- beta(e): stage A0(e+2), B0(e+2), B1(e+2) ----
    stage16(aSrc + k2,               ldsW + 0);
    stage16(aSrc + (128 << 13) + k2, ldsW + 8192);
    stage16(bSrc + k2,               ldsW + 65536);
    stage16(bSrc + (128 << 13) + k2, ldsW + 73728);
    stage16(bSrc + (32 << 13) + k2,  ldsW + 81920);
    stage16(bSrc + (160 << 13) + k2, ldsW + 90112);
    WAIT_VM8_BAR();
    __builtin_amdgcn_s_setprio(1);
    LOADA_TO(afX, 1, 0)                 // A0(o)
    LOADB_TO(bf0B, 1, 0)                // B0(o)
    MFMA16(1, 1, afY, bf1);             // c3 tile e
    sgb_12reads();
    FENCE();
    LOADB_TO(bf1, 1, 1)                 // B1(o)  (after c3 issue: WAR safe)
    MFMA16(1, 0, afY, bf0A);            // c4 tile e
    sgb_4reads();
    __builtin_amdgcn_s_setprio(0);
    FENCE();

    // ---- alpha(o): stage A1(e+2) ----
    stage16(aSrc + (64 << 13) + k2,  ldsW + 16384);
    stage16(aSrc + (192 << 13) + k2, ldsW + 24576);
    WAIT_VM8_BAR();
    __builtin_amdgcn_s_setprio(1);
    LOADA_TO(afY, 1, 1)                 // A1(o)
    MFMA16(0, 0, afX, bf0B);            // c1 tile o
    sgb_8reads();
    FENCE();
    MFMA16(0, 1, afX, bf1);             // c2 tile o (pure MFMA)
    __builtin_amdgcn_s_setprio(0);
    FENCE();

    // ---- beta(o): stage A0(o+2), B0(o+2), B1(o+2) ----
    stage16(aSrc + k3,               ldsW + 32768);
    stage16(aSrc + (128 << 13) + k3, ldsW + 40960);
    stage16(bSrc + k3,               ldsW + 98304);
    stage16(bSrc + (128 << 13) + k3, ldsW + 106496);
    stage16(bSrc + (32 << 13) + k3,  ldsW + 114688);
    stage16(bSrc + (160 << 13) + k3, ldsW + 122880);
    WAIT_VM8_BAR();
    __builtin_amdgcn_s_setprio(1);
    LOADA_TO(afX, 0, 0)                 // A0(e+2)
    LOADB_TO(bf0A, 0, 0)                // B0(e+2)
    MFMA16(1, 1, afY, bf1);             // c3 tile o
    sgb_12reads();
    FENCE();
    LOADB_TO(bf1, 0, 1)                 // B1(e+2) (after c3 issue: WAR safe)
    MFMA16(1, 0, afY, bf0B);            // c4 tile o
    sgb_4reads();
    __builtin_amdgcn_s_setprio(0);
    FENCE();

    kb += 256;
  }

  // ---- epilogue: D row=(lq*4+rr), col=lrow within each 16x16 fragment ----
#pragma unroll
  for (int qm = 0; qm < 2; ++qm)
#pragma unroll
    for (int t = 0; t < 4; ++t)
#pragma unroll
      for (int rr = 0; rr < 4; ++rr) {
        float* cp = C +
            (size_t)(m0 + wm * 128 + qm * 64 + t * 16 + lq * 4 + rr) * D_DIM +
            n0 + wn * 64 + lrow;
#pragma unroll
        for (int qn = 0; qn < 2; ++qn)
#pragma unroll
          for (int j = 0; j < 2; ++j)
            cp[qn * 32 + j * 16] = acc[qm][qn][t][j][rr];
      }
}

extern "C" void kernel_launch(void* const* d_in, const int* in_sizes, int n_in,
                              void* d_out, int out_size, void* d_ws, size_t ws_size,
                              hipStream_t stream) {
  const float* x     = (const float*)d_in[0];  // [M, 4096], M = 8192
  const float* W     = (const float*)d_in[1];  // [4096, 4096]
  const float* lA    = (const float*)d_in[2];  // [16, 4096]
  const float* lB    = (const float*)d_in[3];  // [4096, 16]
  const float* sigma = (const float*)d_in[4];  // [16]
  float* out = (float*)d_out;

  const int M = in_sizes[0] / D_DIM;           // 8192
  // Workspace layout: x_bf16 (M*4096*2 = 64 MB) then W_eff bf16 (32 MB).
  unsigned int* xb = (unsigned int*)d_ws;
  unsigned int* wb = (unsigned int*)((char*)d_ws + (size_t)M * D_DIM * 2);

  const int n8 = in_sizes[0] / 8;              // x octets
  const int nxblocks = (n8 + 255) / 256;       // 16384
  const int nwblocks = (D_DIM * D_DIM / 4) / 256;  // 16384
  prep_kernel<<<nxblocks + nwblocks, 256, 0, stream>>>(
      x, xb, n8, nxblocks, W, lA, lB, sigma, wb);

  const int nblocks = (M / 256) * (D_DIM / 256);   // 32*16 = 512
  gemm_bt_kernel<<<nblocks, 512, 0, stream>>>(
      (const unsigned short*)xb, (const unsigned short*)wb, out, M);
}

// Round 9
// 497.242 us; speedup vs baseline: 1.7469x; 1.5153x over previous
//
#include <hip/hip_runtime.h>

// Problem dims (fixed by setup_inputs): x[4,2048,4096] f32, W[4096,4096] f32,
// lora_A[16,4096], lora_B[4096,16], sigma[16]. out[4,2048,4096] f32.
// out = x @ (W + SCALING * (B*diag(sigma_masked)) @ A)^T
#define D_DIM 4096
#define R_DIM 16
#define SCALING_F 1.0f          // 16.0/16
#define THRESH 0.01f

typedef __attribute__((ext_vector_type(8))) short short8;   // 8 bf16 = 4 VGPRs
typedef __attribute__((ext_vector_type(4))) float floatx4;  // MFMA C/D

__device__ __forceinline__ unsigned int f2bf(float f) {
  union { float f; unsigned int u; } v; v.f = f;
  unsigned int u = v.u;
  u += 0x7FFFu + ((u >> 16) & 1u);   // round-to-nearest-even
  return u >> 16;
}

// ---------- fused prep: x f32->bf16 AND W_eff build, one launch ----------
__global__ __launch_bounds__(256) void prep_kernel(
    const float* __restrict__ x, unsigned int* __restrict__ xb, int n8,
    int nxblocks,
    const float* __restrict__ W, const float* __restrict__ lA,
    const float* __restrict__ lB, const float* __restrict__ sigma,
    unsigned int* __restrict__ wb) {
  __shared__ float Bs[R_DIM];
  int b = blockIdx.x;
  if (b < nxblocks) {
    int idx = b * 256 + threadIdx.x;
    if (idx >= n8) return;
    const float4* xp = (const float4*)x;
    float4 v0 = xp[2 * idx];
    float4 v1 = xp[2 * idx + 1];
    uint4 o;
    o.x = f2bf(v0.x) | (f2bf(v0.y) << 16);
    o.y = f2bf(v0.z) | (f2bf(v0.w) << 16);
    o.z = f2bf(v1.x) | (f2bf(v1.y) << 16);
    o.w = f2bf(v1.z) | (f2bf(v1.w) << 16);
    ((uint4*)xb)[idx] = o;
  } else {
    int idx = (b - nxblocks) * 256 + threadIdx.x;  // float4 index
    int o  = idx >> 10;                             // row (uniform per block)
    int dq = idx & 1023;
    if (threadIdx.x < R_DIM) {
      float s = sigma[threadIdx.x];
      s = (fabsf(s) >= THRESH) ? s : 0.0f;
      Bs[threadIdx.x] = lB[o * R_DIM + threadIdx.x] * s * SCALING_F;
    }
    __syncthreads();
    float4 acc = ((const float4*)W)[idx];
#pragma unroll
    for (int r = 0; r < R_DIM; ++r) {
      float bb = Bs[r];
      float4 a = ((const float4*)(lA + (size_t)r * D_DIM))[dq];
      acc.x += bb * a.x; acc.y += bb * a.y; acc.z += bb * a.z; acc.w += bb * a.w;
    }
    uint2 p;
    p.x = f2bf(acc.x) | (f2bf(acc.y) << 16);
    p.y = f2bf(acc.z) | (f2bf(acc.w) << 16);
    ((uint2*)wb)[idx] = p;
  }
}

// =====================================================================
// GEMM: C[M,N] = A[M,K] * B[N,K]^T, bf16 in, f32 out.
// 256x256 tile, BK=64, 8 waves (2M x 4N), 512 threads, 128 KiB LDS.
//
// R6-verified 8-sub-phase schedule (sgb {1R,2M}/{1R,4M} interleave,
// register-double-buffered fragments, dist-1 consumption, 2 stages/phase)
// with HALVED barrier frequency: vmcnt+s_barrier at even phases only
// (p0/p2/p4/p6). Each barrier publishes two phases of staged data:
// vmcnt(6) at barrier top (after own 2-chunk issue, 10 outstanding)
// drains the 4 oldest chunks = exactly the data read by this phase and
// the following (barrier-free) phase. Register lifetimes are BYTE-
// IDENTICAL to R6 (each phase's read DST consumed next phase) — the
// R7/R8 2-phase regressions came from merged register phases (spill:
// WRITE_SIZE 131->367/166 MB); this keeps R6's no-spill plan.
//
// Publication/overwrite ledger (verified per phase): odd-phase reads
// consume chunks drained by each wave's own vmcnt(6) before the
// preceding even barrier; every LDS overwrite at phase p targets a slot
// whose last reads (p-4) completed before the barrier at p-2 or p-4+1,
// with >=2000 cyc issue-to-land margin vs ~120cyc ds_read in-flight.
// Prologue stages A0(0),B0(0),B1(0),A1(0),A0(1),B0(1) and waits
// vmcnt(8) (drains only A0(0),B0(0) for the pre-loop reads), leaving
// B1(0),A1(0),A0(1),B0(1) in flight so p0/p2's vmcnt(6) drains land
// exactly on the f=0 reads. Tail stages wrap &8191 (read-but-unused).
//
// LDS map (bytes): A-buf0 @0, A-buf1 @32768, B-buf0 @65536, B-buf1 @98304;
// slot A0/B0 @+0, A1/B1 @+16384 within each buf; buf = tile parity.
// 16B-granule XOR swizzle: slot s holds kgroup s^(row&7); inverse applied
// to GLOBAL source addr (linear LDS dest), same XOR on ds_read. 0 conflicts.
// =====================================================================

__device__ __forceinline__ void stage16(const void* g, void* l) {
  __builtin_amdgcn_global_load_lds(
      (const __attribute__((address_space(1))) void*)g,
      (__attribute__((address_space(3))) void*)l, 16, 0, 0);
}

#define FENCE() __builtin_amdgcn_sched_barrier(0)

#define WAIT_VM6_BAR()                                  \
  FENCE();                                              \
  asm volatile("s_waitcnt vmcnt(6)" ::: "memory");      \
  __builtin_amdgcn_s_barrier();                         \
  FENCE()

// Interleave patterns for a fenced {ds_read + MFMA} sub-region.
__device__ __forceinline__ void sgb_8reads() {   // 8 DS_READ + 16 MFMA
#pragma unroll
  for (int i = 0; i < 8; ++i) {
    __builtin_amdgcn_sched_group_barrier(0x100, 1, 0);
    __builtin_amdgcn_sched_group_barrier(0x008, 2, 0);
  }
}
__device__ __forceinline__ void sgb_4reads() {   // 4 DS_READ + 16 MFMA
#pragma unroll
  for (int i = 0; i < 4; ++i) {
    __builtin_amdgcn_sched_group_barrier(0x100, 1, 0);
    __builtin_amdgcn_sched_group_barrier(0x008, 4, 0);
  }
}

#define LOADA_TO(DST, BUF, QM)                                                 \
  _Pragma("unroll") for (int t = 0; t < 4; ++t) {                              \
    DST[t][0] = *(const short8*)(aRd0 + (BUF)*32768 + (QM)*16384 + t*2048);    \
    DST[t][1] = *(const short8*)(aRd1 + (BUF)*32768 + (QM)*16384 + t*2048);    \
  }

#define LOADB_TO(DST, BUF, QN)                                                 \
  _Pragma("unroll") for (int j = 0; j < 2; ++j) {                              \
    DST[j][0] = *(const short8*)(bRd0 + (BUF)*32768 + (QN)*16384 + j*2048);    \
    DST[j][1] = *(const short8*)(bRd1 + (BUF)*32768 + (QN)*16384 + j*2048);    \
  }

#define MFMA16(QM, QN, AF, BF)                                                 \
  _Pragma("unroll") for (int t = 0; t < 4; ++t)                                \
  _Pragma("unroll") for (int j = 0; j < 2; ++j)                                \
    acc[QM][QN][t][j] = __builtin_amdgcn_mfma_f32_16x16x32_bf16(               \
        AF[t][0], BF[j][0], acc[QM][QN][t][j], 0, 0, 0);                       \
  _Pragma("unroll") for (int t = 0; t < 4; ++t)                                \
  _Pragma("unroll") for (int j = 0; j < 2; ++j)                                \
    acc[QM][QN][t][j] = __builtin_amdgcn_mfma_f32_16x16x32_bf16(               \
        AF[t][1], BF[j][1], acc[QM][QN][t][j], 0, 0, 0);

__global__ __launch_bounds__(512, 2) void gemm_bt_kernel(
    const unsigned short* __restrict__ A,   // x bf16 [M, K]
    const unsigned short* __restrict__ B,   // W_eff bf16 [N, K]
    float* __restrict__ C, int M) {
  __shared__ __align__(16) char lds[131072];

  const int tid  = threadIdx.x;
  const int lane = tid & 63;
  const int wave = tid >> 6;      // 0..7
  const int wm   = wave >> 2;     // 0..1 (128 rows each)
  const int wn   = wave & 3;      // 0..3 (64 cols each)
  const int lrow = lane & 15;
  const int lq   = lane >> 4;     // 0..3
  const int r7   = lrow & 7;

  // XCD-bijective block swizzle (gridDim.x % 8 == 0 here: 512 blocks).
  const int bid = blockIdx.x;
  const int cpx = gridDim.x >> 3;
  const int swz = (bid & 7) * cpx + (bid >> 3);
  const int m0 = (swz >> 4) << 8;           // 16 n-tiles (D_DIM/256)
  const int n0 = (swz & 15) << 8;

  // ---- staging source bases (per thread) ----
  const int rr8  = tid >> 3;                               // 0..63
  const int kgsw = (tid & 7) ^ (rr8 & 7);
  const char* aSrc = (const char*)A + ((size_t)(m0 + rr8) << 13) + (kgsw << 4);
  const int nrow = (rr8 & 31) | ((rr8 & 32) << 1);
  const char* bSrc = (const char*)B + ((size_t)(n0 + nrow) << 13) + (kgsw << 4);
  char* ldsW = lds + wave * 1024;           // wave-uniform dest base

  // ---- fragment read bases (per lane) ----
  const char* aRd0 = lds + wm * 8192 + lrow * 128 + ((lq ^ r7) << 4);
  const char* aRd1 = lds + wm * 8192 + lrow * 128 + (((4 | lq) ^ r7) << 4);
  const char* bRd0 = lds + 65536 + wn * 4096 + lrow * 128 + ((lq ^ r7) << 4);
  const char* bRd1 = lds + 65536 + wn * 4096 + lrow * 128 + (((4 | lq) ^ r7) << 4);

  short8 afX[4][2], afY[4][2];          // A0 / A1 fragments (current tile)
  short8 bf0A[2][2], bf0B[2][2];        // B0 fragments (tile parity)
  short8 bf1[2][2];                     // B1 fragments (current tile)
  floatx4 acc[2][2][4][2] = {};         // [qm][qn][t][j]

  // ---- prologue: A0(0),B0(0),B1(0),A1(0),A0(1),B0(1); drain first 4 ----
  stage16(aSrc,                      ldsW + 0);        // A0(0)
  stage16(aSrc + (128 << 13),        ldsW + 8192);
  stage16(bSrc,                      ldsW + 65536);    // B0(0)
  stage16(bSrc + (128 << 13),        ldsW + 73728);
  stage16(bSrc + (32 << 13),         ldsW + 81920);    // B1(0)
  stage16(bSrc + (160 << 13),        ldsW + 90112);
  stage16(aSrc + (64 << 13),         ldsW + 16384);    // A1(0)
  stage16(aSrc + (192 << 13),        ldsW + 24576);
  stage16(aSrc + 128,                ldsW + 32768);    // A0(1) -> buf1
  stage16(aSrc + (128 << 13) + 128,  ldsW + 40960);
  stage16(bSrc + 128,                ldsW + 98304);    // B0(1) -> buf1
  stage16(bSrc + (128 << 13) + 128,  ldsW + 106496);
  FENCE();
  asm volatile("s_waitcnt vmcnt(8)" ::: "memory");     // A0(0),B0(0) landed
  __builtin_amdgcn_s_barrier();
  FENCE();
  LOADA_TO(afX, 0, 0)                                  // A0(0)
  LOADB_TO(bf0A, 0, 0)                                 // B0(0)
  FENCE();

  int kb = 0;
#pragma unroll 1
  for (int f = 0; f < 32; ++f) {             // 64 K-tiles, 2 per frame
    const int k1 = (kb + 128) & 8191;        // tile o = 2f+1
    const int k2 = (kb + 256) & 8191;        // tile e+2 (wraps at tail)
    const int k3 = (kb + 384) & 8191;        // tile o+2 (wraps at tail)

    // p0 [BARRIER]: c1(e)=A0*B0 | stage B1(o)->buf1 | read bf1 <- B1(e)
    stage16(bSrc + (32 << 13) + k1,  ldsW + 114688);
    stage16(bSrc + (160 << 13) + k1, ldsW + 122880);
    WAIT_VM6_BAR();                          // drains B1(e), A1(e)
    __builtin_amdgcn_s_setprio(1);
    LOADB_TO(bf1, 0, 1)
    MFMA16(0, 0, afX, bf0A);
    sgb_4reads();
    __builtin_amdgcn_s_setprio(0);
    FENCE();

    // p1: c2(e)=A0*B1 | stage A1(o)->buf1 | read afY <- A1(e)  (no barrier)
    stage16(aSrc + (64 << 13) + k1,  ldsW + 49152);
    stage16(aSrc + (192 << 13) + k1, ldsW + 57344);
    FENCE();
    __builtin_amdgcn_s_setprio(1);
    LOADA_TO(afY, 0, 1)
    MFMA16(0, 1, afX, bf1);
    sgb_8reads();
    __builtin_amdgcn_s_setprio(0);
    FENCE();

    // p2 [BARRIER]: c3(e)=A1*B1 | stage A0(e+2)->buf0 | read afX <- A0(o)
    stage16(aSrc + k2,               ldsW + 0);
    stage16(aSrc + (128 << 13) + k2, ldsW + 8192);
    WAIT_VM6_BAR();                          // drains A0(o), B0(o)
    __builtin_amdgcn_s_setprio(1);
    LOADA_TO(afX, 1, 0)
    MFMA16(1, 1, afY, bf1);
    sgb_8reads();
    __builtin_amdgcn_s_setprio(0);
    FENCE();

    // p3: c4(e)=A1*B0 | stage B0(e+2)->buf0 | read bf0B <- B0(o) (no barrier)
    stage16(bSrc + k2,               ldsW + 65536);
    stage16(bSrc + (128 << 13) + k2, ldsW + 73728);
    FENCE();
    __builtin_amdgcn_s_setprio(1);
    LOADB_TO(bf0B, 1, 0)
    MFMA16(1, 0, afY, bf0A);
    sgb_4reads();
    __builtin_amdgcn_s_setprio(0);
    FENCE();

    // p4 [BARRIER]: c1(o)=A0*B0 | stage B1(e+2)->buf0 | read bf1 <- B1(o)
    stage16(bSrc + (32 << 13) + k2,  ldsW + 81920);
    stage16(bSrc + (160 << 13) + k2, ldsW + 90112);
    WAIT_VM6_BAR();                          // drains B1(o), A1(o)
    __builtin_amdgcn_s_setprio(1);
    LOADB_TO(bf1, 1, 1)
    MFMA16(0, 0, afX, bf0B);
    sgb_4reads();
    __builtin_amdgcn_s_setprio(0);
    FENCE();

    // p5: c2(o)=A0*B1 | stage A1(e+2)->buf0 | read afY <- A1(o) (no barrier)
    stage16(aSrc + (64 << 13) + k2,  ldsW + 16384);
    stage16(aSrc + (192 << 13) + k2, ldsW + 24576);
    FENCE();
    __builtin_amdgcn_s_setprio(1);
    LOADA_TO(afY, 1, 1)
    MFMA16(0, 1, afX, bf1);
    sgb_8reads();
    __builtin_amdgcn_s_setprio(0);
    FENCE();

    // p6 [BARRIER]: c3(o)=A1*B1 | stage A0(o+2)->buf1 | read afX <- A0(e+2)
    stage16(aSrc + k3,               ldsW + 32768);
    stage16(aSrc + (128 << 13) + k3, ldsW + 40960);
    WAIT_VM6_BAR();                          // drains A0(e+2), B0(e+2)
    __builtin_amdgcn_s_setprio(1);
    LOADA_TO(afX, 0, 0)
    MFMA16(1, 1, afY, bf1);
    sgb_8reads();
    __builtin_amdgcn_s_setprio(0);
    FENCE();

    // p7: c4(o)=A1*B0 | stage B0(o+2)->buf1 | read bf0A <- B0(e+2) (no barrier)
    stage16(bSrc + k3,               ldsW + 98304);
    stage16(bSrc + (128 << 13) + k3, ldsW + 106496);
    FENCE();
    __builtin_amdgcn_s_setprio(1);
    LOADB_TO(bf0A, 0, 0)
    MFMA16(1, 0, afY, bf0B);
    sgb_4reads();
    __builtin_amdgcn_s_setprio(0);
    FENCE();

    kb += 256;
  }

  // ---- epilogue: D row=(lq*4+rr), col=lrow within each 16x16 fragment ----
#pragma unroll
  for (int qm = 0; qm < 2; ++qm)
#pragma unroll
    for (int t = 0; t < 4; ++t)
#pragma unroll
      for (int rr = 0; rr < 4; ++rr) {
        float* cp = C +
            (size_t)(m0 + wm * 128 + qm * 64 + t * 16 + lq * 4 + rr) * D_DIM +
            n0 + wn * 64 + lrow;
#pragma unroll
        for (int qn = 0; qn < 2; ++qn)
#pragma unroll
          for (int j = 0; j < 2; ++j)
            cp[qn * 32 + j * 16] = acc[qm][qn][t][j][rr];
      }
}

extern "C" void kernel_launch(void* const* d_in, const int* in_sizes, int n_in,
                              void* d_out, int out_size, void* d_ws, size_t ws_size,
                              hipStream_t stream) {
  const float* x     = (const float*)d_in[0];  // [M, 4096], M = 8192
  const float* W     = (const float*)d_in[1];  // [4096, 4096]
  const float* lA    = (const float*)d_in[2];  // [16, 4096]
  const float* lB    = (const float*)d_in[3];  // [4096, 16]
  const float* sigma = (const float*)d_in[4];  // [16]
  float* out = (float*)d_out;

  const int M = in_sizes[0] / D_DIM;           // 8192
  // Workspace layout: x_bf16 (M*4096*2 = 64 MB) then W_eff bf16 (32 MB).
  unsigned int* xb = (unsigned int*)d_ws;
  unsigned int* wb = (unsigned int*)((char*)d_ws + (size_t)M * D_DIM * 2);

  const int n8 = in_sizes[0] / 8;              // x octets
  const int nxblocks = (n8 + 255) / 256;       // 16384
  const int nwblocks = (D_DIM * D_DIM / 4) / 256;  // 16384
  prep_kernel<<<nxblocks + nwblocks, 256, 0, stream>>>(
      x, xb, n8, nxblocks, W, lA, lB, sigma, wb);

  const int nblocks = (M / 256) * (D_DIM / 256);   // 32*16 = 512
  gemm_bt_kernel<<<nblocks, 512, 0, stream>>>(
      (const unsigned short*)xb, (const unsigned short*)wb, out, M);
}